// Round 1
// baseline (2408.498 us; speedup 1.0000x reference)
//
#include <hip/hip_runtime.h>

#define NPTS 262144
#define DIM 128
#define KCL 512

constexpr float DECAY = 0.99f;
constexpr float EPSV = 1e-5f;
constexpr float CCOST = 0.25f;

// ---- output layout (floats) ----
#define O_ZQ 0
#define O_LOSS (NPTS * DIM)            // 33554432
#define O_IDX (O_LOSS + 1)             // 33554433
#define O_NECS (O_IDX + NPTS)          // 33816577
#define O_NEMAW (O_NECS + KCL)         // 33817089
#define O_NEMB (O_NEMAW + KCL * DIM)   // 33882625

// ---- workspace layout (4-byte units) ----
#define W_ENORM 0                      // f32[512]
#define W_COUNTS 512                   // u32[512]
#define W_LOSS 1024                    // f32[1]
#define W_CS 1032                      // f32[512]
#define W_OFF 1544                     // u32[512]
#define W_CUR 2056                     // u32[512]
#define W_IDX 4096                     // i32[N]
#define W_SORTED (W_IDX + NPTS)        // u32[N]

// ---- k_main tiling ----
#define MT 64       // points per block
#define KT 64       // clusters per tile
#define DTL 32      // d per LDS e-tile
#define LDZ 68      // padded stride (16B aligned rows, breaks bank conflicts)
#define LDE 68
#define MARGIN 0.02f

__global__ void k_enorm(const float* __restrict__ emb, float* __restrict__ wsf) {
    int k = blockIdx.x * blockDim.x + threadIdx.x;
    if (k < KCL) {
        const float4* row = (const float4*)(emb + (size_t)k * DIM);
        float s = 0.0f;
#pragma unroll
        for (int i = 0; i < DIM / 4; i++) {
            float4 v = row[i];
            s += v.x * v.x + v.y * v.y + v.z * v.z + v.w * v.w;
        }
        wsf[W_ENORM + k] = s;
    }
}

struct RedS {
    float r1v[MT * 17];
    float r2v[MT * 17];
    int r1i[MT * 17];
    int r2i[MT * 17];
    int ish[MT];
};

struct SharedU {
    float zt[DIM * LDZ];   // z tile, transposed [d][p]
    union {
        float et[DTL * LDE];  // e tile, transposed [d][k]
        RedS red;
    } u;
};

__global__ __launch_bounds__(256, 3) void k_main(
    const float* __restrict__ z, const float* __restrict__ emb,
    float* __restrict__ out, float* __restrict__ wsf,
    unsigned* __restrict__ wsu, int* __restrict__ wsi) {
    __shared__ SharedU sm;
    const int t = threadIdx.x;
    const int blk = blockIdx.x;
    const int tp = t & 15;   // point group 0..15 (4 points each)
    const int tk = t >> 4;   // cluster group 0..15 (4 clusters each)

    // ---- stage z tile transposed: zt[d][p] ----
    {
        const float* zsrc = z + (size_t)blk * MT * DIM;
#pragma unroll
        for (int i = 0; i < (MT * DIM) / 256; i++) {
            int f = t + 256 * i;
            int p = f >> 7, d = f & 127;
            sm.zt[d * LDZ + p] = zsrc[f];
        }
    }

    float b1v[4], b2v[4];
    int b1i[4], b2i[4];
#pragma unroll
    for (int pi = 0; pi < 4; pi++) { b1v[pi] = 3.4e38f; b2v[pi] = 3.4e38f; b1i[pi] = 0; b2i[pi] = 0; }

    const float* enorm = wsf + W_ENORM;

    for (int kt = 0; kt < KCL / KT; kt++) {
        float acc[4][4];
#pragma unroll
        for (int pi = 0; pi < 4; pi++)
#pragma unroll
            for (int ki = 0; ki < 4; ki++) acc[pi][ki] = 0.0f;

        for (int dt = 0; dt < DIM / DTL; dt++) {
            __syncthreads();  // protect et reuse (and zt staging on first iter)
            // stage e tile transposed: et[d][k], 64 clusters x 32 d
#pragma unroll
            for (int i = 0; i < 2; i++) {
                int g = t + 256 * i;       // 0..511 float4s
                int k = g >> 3;            // 0..63
                int dq = g & 7;            // float4 idx within 32 d
                float4 v = *(const float4*)(emb + (size_t)(kt * KT + k) * DIM + dt * DTL + 4 * dq);
                sm.u.et[(4 * dq + 0) * LDE + k] = v.x;
                sm.u.et[(4 * dq + 1) * LDE + k] = v.y;
                sm.u.et[(4 * dq + 2) * LDE + k] = v.z;
                sm.u.et[(4 * dq + 3) * LDE + k] = v.w;
            }
            __syncthreads();
            // register-tiled dot accumulation
#pragma unroll 8
            for (int d = 0; d < DTL; d++) {
                float4 za = *(const float4*)&sm.zt[(dt * DTL + d) * LDZ + 4 * tp];
                float4 ea = *(const float4*)&sm.u.et[d * LDE + 4 * tk];
                float zs[4] = {za.x, za.y, za.z, za.w};
                float es[4] = {ea.x, ea.y, ea.z, ea.w};
#pragma unroll
                for (int pi = 0; pi < 4; pi++)
#pragma unroll
                    for (int ki = 0; ki < 4; ki++) acc[pi][ki] += zs[pi] * es[ki];
            }
        }
        // distance epilogue + per-thread top-2 (tie -> lowest index, matching np.argmin)
#pragma unroll
        for (int ki = 0; ki < 4; ki++) {
            int k = kt * KT + 4 * tk + ki;
            float en = enorm[k];
#pragma unroll
            for (int pi = 0; pi < 4; pi++) {
                float dist = en - 2.0f * acc[pi][ki];
                bool lt1 = (dist < b1v[pi]) || (dist == b1v[pi] && k < b1i[pi]);
                bool lt2 = (dist < b2v[pi]) || (dist == b2v[pi] && k < b2i[pi]);
                if (lt1) {
                    b2v[pi] = b1v[pi]; b2i[pi] = b1i[pi];
                    b1v[pi] = dist; b1i[pi] = k;
                } else if (lt2) {
                    b2v[pi] = dist; b2i[pi] = k;
                }
            }
        }
    }

    __syncthreads();  // et -> red union transition
#pragma unroll
    for (int pi = 0; pi < 4; pi++) {
        int p = 4 * tp + pi;
        sm.u.red.r1v[p * 17 + tk] = b1v[pi];
        sm.u.red.r2v[p * 17 + tk] = b2v[pi];
        sm.u.red.r1i[p * 17 + tk] = b1i[pi];
        sm.u.red.r2i[p * 17 + tk] = b2i[pi];
    }
    __syncthreads();

    float contrib = 0.0f;
    if (t < MT) {
        int p = t;
        float v1 = 3.4e38f, v2 = 3.4e38f;
        int i1 = 0, i2 = 0;
        for (int j = 0; j < 16; j++) {
            float c1 = sm.u.red.r1v[p * 17 + j];
            int ci1 = sm.u.red.r1i[p * 17 + j];
            float c2 = sm.u.red.r2v[p * 17 + j];
            int ci2 = sm.u.red.r2i[p * 17 + j];
            if (c1 < v1 || (c1 == v1 && ci1 < i1)) { v2 = v1; i2 = i1; v1 = c1; i1 = ci1; }
            else if (c1 < v2 || (c1 == v2 && ci1 < i2)) { v2 = c1; i2 = ci1; }
            if (c2 < v1 || (c2 == v1 && ci2 < i1)) { v2 = v1; i2 = i1; v1 = c2; i1 = ci2; }
            else if (c2 < v2 || (c2 == v2 && ci2 < i2)) { v2 = c2; i2 = ci2; }
        }
        // ||z_p||^2 from LDS (2-way bank aliasing = free)
        float zn = 0.0f;
        for (int d = 0; d < DIM; d++) {
            float zv = sm.zt[d * LDZ + p];
            zn += zv * zv;
        }
        int fi = i1;
        float fdist;
        if (v2 - v1 < MARGIN) {
            // near-tie: fp64 re-check of both candidates (rare path)
            double d1 = 0.0, d2 = 0.0;
            for (int d = 0; d < DIM; d++) {
                double zv = (double)sm.zt[d * LDZ + p];
                double e1 = (double)emb[(size_t)i1 * DIM + d];
                double e2 = (double)emb[(size_t)i2 * DIM + d];
                double t1 = zv - e1, t2 = zv - e2;
                d1 += t1 * t1;
                d2 += t2 * t2;
            }
            if (d2 < d1 || (d2 == d1 && i2 < i1)) { fi = i2; fdist = (float)d2; }
            else { fdist = (float)d1; }
        } else {
            fdist = v1 + zn;  // ||z-e||^2 = dist + ||z||^2
        }
        contrib = fdist;
        sm.u.red.ish[p] = fi;
        int gp = blk * MT + p;
        out[O_IDX + gp] = (float)fi;    // harness reads d_out as fp32
        wsi[W_IDX + gp] = fi;
        atomicAdd(&wsu[W_COUNTS + fi], 1u);
    }
    // loss partial: wave-0 reduction, one atomic per block
    if (t < 64) {
        for (int o = 32; o > 0; o >>= 1) contrib += __shfl_down(contrib, o, 64);
        if (t == 0) atomicAdd(&wsf[W_LOSS], contrib);
    }
    __syncthreads();
    // z_q gather (straight-through output == z_q numerically)
    float* outz = out + (size_t)blk * MT * DIM;
#pragma unroll
    for (int i = 0; i < (MT * DIM) / (256 * 4); i++) {
        int f4 = t + 256 * i;  // float4 index
        int p = f4 >> 5;
        int dq = f4 & 31;
        int ci = sm.u.red.ish[p];
        float4 v = *(const float4*)(emb + (size_t)ci * DIM + 4 * dq);
        *((float4*)outz + f4) = v;
    }
}

__global__ void k_finalize(const float* __restrict__ ema_cs, float* __restrict__ out,
                           float* __restrict__ wsf, unsigned* __restrict__ wsu) {
    __shared__ float s[KCL];
    __shared__ unsigned sc[KCL];
    int t = threadIdx.x;  // 512 threads
    unsigned c = wsu[W_COUNTS + t];
    float necs = ema_cs[t] * DECAY + (1.0f - DECAY) * (float)c;
    out[O_NECS + t] = necs;
    s[t] = necs;
    __syncthreads();
    for (int o = 256; o > 0; o >>= 1) {
        if (t < o) s[t] += s[t + o];
        __syncthreads();
    }
    float n = s[0];
    float cs = (necs + EPSV) / (n + (float)KCL * EPSV) * n;
    wsf[W_CS + t] = cs;
    // exclusive prefix sum of counts (Hillis-Steele)
    sc[t] = c;
    __syncthreads();
    for (int o = 1; o < KCL; o <<= 1) {
        unsigned v = (t >= o) ? sc[t - o] : 0u;
        __syncthreads();
        sc[t] += v;
        __syncthreads();
    }
    unsigned excl = sc[t] - c;
    wsu[W_OFF + t] = excl;
    wsu[W_CUR + t] = excl;
    if (t == 0) out[O_LOSS] = CCOST * wsf[W_LOSS] / (float)((size_t)NPTS * DIM);
}

__global__ void k_scatter(unsigned* __restrict__ wsu, const int* __restrict__ wsi) {
    int p = blockIdx.x * blockDim.x + threadIdx.x;
    int k = wsi[W_IDX + p];
    unsigned pos = atomicAdd(&wsu[W_CUR + k], 1u);
    wsu[W_SORTED + pos] = (unsigned)p;
}

__global__ __launch_bounds__(256) void k_dw(
    const float* __restrict__ z, const float* __restrict__ ema_w,
    float* __restrict__ out, const float* __restrict__ wsf,
    const unsigned* __restrict__ wsu) {
    __shared__ float part[2][DIM];
    int k = blockIdx.x;
    int t = threadIdx.x;
    int r = t >> 7, d = t & 127;
    unsigned base = wsu[W_OFF + k];
    unsigned cnt = wsu[W_COUNTS + k];
    float acc = 0.0f;
    unsigned j = r;
    for (; j + 8 <= cnt; j += 8) {
        unsigned p0 = wsu[W_SORTED + base + j];
        unsigned p1 = wsu[W_SORTED + base + j + 2];
        unsigned p2 = wsu[W_SORTED + base + j + 4];
        unsigned p3 = wsu[W_SORTED + base + j + 6];
        acc += z[(size_t)p0 * DIM + d];
        acc += z[(size_t)p1 * DIM + d];
        acc += z[(size_t)p2 * DIM + d];
        acc += z[(size_t)p3 * DIM + d];
    }
    for (; j < cnt; j += 2) {
        unsigned p = wsu[W_SORTED + base + j];
        acc += z[(size_t)p * DIM + d];
    }
    part[r][d] = acc;
    __syncthreads();
    if (t < DIM) {
        float dw = part[0][t] + part[1][t];
        float nw = ema_w[(size_t)k * DIM + t] * DECAY + (1.0f - DECAY) * dw;
        out[O_NEMAW + k * DIM + t] = nw;
        out[O_NEMB + k * DIM + t] = nw / wsf[W_CS + k];
    }
}

extern "C" void kernel_launch(void* const* d_in, const int* in_sizes, int n_in,
                              void* d_out, int out_size, void* d_ws, size_t ws_size,
                              hipStream_t stream) {
    const float* z = (const float*)d_in[0];
    const float* emb = (const float*)d_in[1];
    const float* ema_cs = (const float*)d_in[2];
    const float* ema_w = (const float*)d_in[3];
    float* out = (float*)d_out;
    float* wsf = (float*)d_ws;
    unsigned* wsu = (unsigned*)d_ws;
    int* wsi = (int*)d_ws;

    // zero counts[512] + loss[1] (ws is re-poisoned 0xAA before every launch)
    hipMemsetAsync((char*)d_ws + (size_t)W_COUNTS * 4, 0, 513 * 4, stream);

    k_enorm<<<2, 256, 0, stream>>>(emb, wsf);
    k_main<<<NPTS / MT, 256, 0, stream>>>(z, emb, out, wsf, wsu, wsi);
    k_finalize<<<1, KCL, 0, stream>>>(ema_cs, out, wsf, wsu);
    k_scatter<<<NPTS / 256, 256, 0, stream>>>(wsu, wsi);
    k_dw<<<KCL, 256, 0, stream>>>(z, ema_w, out, wsf, wsu);
}

// Round 2
// 1287.710 us; speedup vs baseline: 1.8704x; 1.8704x over previous
//
#include <hip/hip_runtime.h>

#define NPTS 262144
#define DIM 128
#define KCL 512

constexpr float DECAY = 0.99f;
constexpr float EPSV = 1e-5f;
constexpr float CCOST = 0.25f;

// ---- output layout (floats) ----
#define O_ZQ 0
#define O_LOSS (NPTS * DIM)            // 33554432
#define O_IDX (O_LOSS + 1)             // 33554433
#define O_NECS (O_IDX + NPTS)          // 33816577
#define O_NEMAW (O_NECS + KCL)         // 33817089
#define O_NEMB (O_NEMAW + KCL * DIM)   // 33882625

// ---- workspace layout (4-byte units) ----
#define W_ENORM 0                      // f32[512]
#define W_COUNTS 512                   // u32[512]
#define W_LOSS 1024                    // f32[1]
#define W_DW 1088                      // f32[512*128] -- zeroed
#define W_CS 66624                     // f32[512]
#define W_OFF 67136                    // u32[513]
#define W_CUR 67712                    // u32[512]
#define W_IDX 68224                    // i32[N]
#define W_SORTED (W_IDX + NPTS)        // u32[N]

// ---- k_main tiling ----
#define MT 64       // points per block
#define KT 64       // clusters per tile
#define DTL 32      // d per LDS e-tile
#define LDZ 68
#define LDE 68
#define MARGIN 0.02f

// ---- k_dwseg ----
#define SEG 64      // sorted entries per block

__global__ void k_enorm(const float* __restrict__ emb, float* __restrict__ wsf) {
    int k = blockIdx.x * blockDim.x + threadIdx.x;
    if (k < KCL) {
        const float4* row = (const float4*)(emb + (size_t)k * DIM);
        float s = 0.0f;
#pragma unroll
        for (int i = 0; i < DIM / 4; i++) {
            float4 v = row[i];
            s += v.x * v.x + v.y * v.y + v.z * v.z + v.w * v.w;
        }
        wsf[W_ENORM + k] = s;
    }
}

struct RedS {
    float r1v[MT * 17];
    float r2v[MT * 17];
    int r1i[MT * 17];
    int r2i[MT * 17];
    int ish[MT];
};

struct SharedU {
    float zt[DIM * LDZ];   // z tile, transposed [d][p]
    union {
        float et[DTL * LDE];  // e tile, transposed [d][k]
        RedS red;
    } u;
};

__global__ __launch_bounds__(256, 3) void k_main(
    const float* __restrict__ z, const float* __restrict__ emb,
    float* __restrict__ out, float* __restrict__ wsf,
    unsigned* __restrict__ wsu, int* __restrict__ wsi) {
    __shared__ SharedU sm;
    const int t = threadIdx.x;
    const int blk = blockIdx.x;
    const int tp = t & 15;   // point group 0..15 (4 points each)
    const int tk = t >> 4;   // cluster group 0..15 (4 clusters each)

    // ---- stage z tile transposed: zt[d][p] ----
    {
        const float* zsrc = z + (size_t)blk * MT * DIM;
#pragma unroll
        for (int i = 0; i < (MT * DIM) / 256; i++) {
            int f = t + 256 * i;
            int p = f >> 7, d = f & 127;
            sm.zt[d * LDZ + p] = zsrc[f];
        }
    }

    float b1v[4], b2v[4];
    int b1i[4], b2i[4];
#pragma unroll
    for (int pi = 0; pi < 4; pi++) { b1v[pi] = 3.4e38f; b2v[pi] = 3.4e38f; b1i[pi] = 0; b2i[pi] = 0; }

    const float* enorm = wsf + W_ENORM;

    for (int kt = 0; kt < KCL / KT; kt++) {
        float acc[4][4];
#pragma unroll
        for (int pi = 0; pi < 4; pi++)
#pragma unroll
            for (int ki = 0; ki < 4; ki++) acc[pi][ki] = 0.0f;

        for (int dt = 0; dt < DIM / DTL; dt++) {
            __syncthreads();  // protect et reuse (and zt staging on first iter)
            // stage e tile transposed: et[d][k], 64 clusters x 32 d
#pragma unroll
            for (int i = 0; i < 2; i++) {
                int g = t + 256 * i;       // 0..511 float4s
                int k = g >> 3;            // 0..63
                int dq = g & 7;            // float4 idx within 32 d
                float4 v = *(const float4*)(emb + (size_t)(kt * KT + k) * DIM + dt * DTL + 4 * dq);
                sm.u.et[(4 * dq + 0) * LDE + k] = v.x;
                sm.u.et[(4 * dq + 1) * LDE + k] = v.y;
                sm.u.et[(4 * dq + 2) * LDE + k] = v.z;
                sm.u.et[(4 * dq + 3) * LDE + k] = v.w;
            }
            __syncthreads();
            // register-tiled dot accumulation
#pragma unroll 8
            for (int d = 0; d < DTL; d++) {
                float4 za = *(const float4*)&sm.zt[(dt * DTL + d) * LDZ + 4 * tp];
                float4 ea = *(const float4*)&sm.u.et[d * LDE + 4 * tk];
                float zs[4] = {za.x, za.y, za.z, za.w};
                float es[4] = {ea.x, ea.y, ea.z, ea.w};
#pragma unroll
                for (int pi = 0; pi < 4; pi++)
#pragma unroll
                    for (int ki = 0; ki < 4; ki++) acc[pi][ki] += zs[pi] * es[ki];
            }
        }
        // distance epilogue + per-thread top-2 (tie -> lowest index, matching np.argmin)
#pragma unroll
        for (int ki = 0; ki < 4; ki++) {
            int k = kt * KT + 4 * tk + ki;
            float en = enorm[k];
#pragma unroll
            for (int pi = 0; pi < 4; pi++) {
                float dist = en - 2.0f * acc[pi][ki];
                bool lt1 = (dist < b1v[pi]) || (dist == b1v[pi] && k < b1i[pi]);
                bool lt2 = (dist < b2v[pi]) || (dist == b2v[pi] && k < b2i[pi]);
                if (lt1) {
                    b2v[pi] = b1v[pi]; b2i[pi] = b1i[pi];
                    b1v[pi] = dist; b1i[pi] = k;
                } else if (lt2) {
                    b2v[pi] = dist; b2i[pi] = k;
                }
            }
        }
    }

    __syncthreads();  // et -> red union transition
#pragma unroll
    for (int pi = 0; pi < 4; pi++) {
        int p = 4 * tp + pi;
        sm.u.red.r1v[p * 17 + tk] = b1v[pi];
        sm.u.red.r2v[p * 17 + tk] = b2v[pi];
        sm.u.red.r1i[p * 17 + tk] = b1i[pi];
        sm.u.red.r2i[p * 17 + tk] = b2i[pi];
    }
    __syncthreads();

    float contrib = 0.0f;
    if (t < MT) {
        int p = t;
        float v1 = 3.4e38f, v2 = 3.4e38f;
        int i1 = 0, i2 = 0;
        for (int j = 0; j < 16; j++) {
            float c1 = sm.u.red.r1v[p * 17 + j];
            int ci1 = sm.u.red.r1i[p * 17 + j];
            float c2 = sm.u.red.r2v[p * 17 + j];
            int ci2 = sm.u.red.r2i[p * 17 + j];
            if (c1 < v1 || (c1 == v1 && ci1 < i1)) { v2 = v1; i2 = i1; v1 = c1; i1 = ci1; }
            else if (c1 < v2 || (c1 == v2 && ci1 < i2)) { v2 = c1; i2 = ci1; }
            if (c2 < v1 || (c2 == v1 && ci2 < i1)) { v2 = v1; i2 = i1; v1 = c2; i1 = ci2; }
            else if (c2 < v2 || (c2 == v2 && ci2 < i2)) { v2 = c2; i2 = ci2; }
        }
        // ||z_p||^2 from LDS
        float zn = 0.0f;
        for (int d = 0; d < DIM; d++) {
            float zv = sm.zt[d * LDZ + p];
            zn += zv * zv;
        }
        int fi = i1;
        float fdist;
        if (v2 - v1 < MARGIN) {
            // near-tie: fp64 re-check of both candidates (rare path)
            double d1 = 0.0, d2 = 0.0;
            for (int d = 0; d < DIM; d++) {
                double zv = (double)sm.zt[d * LDZ + p];
                double e1 = (double)emb[(size_t)i1 * DIM + d];
                double e2 = (double)emb[(size_t)i2 * DIM + d];
                double t1 = zv - e1, t2 = zv - e2;
                d1 += t1 * t1;
                d2 += t2 * t2;
            }
            if (d2 < d1 || (d2 == d1 && i2 < i1)) { fi = i2; fdist = (float)d2; }
            else { fdist = (float)d1; }
        } else {
            fdist = v1 + zn;  // ||z-e||^2 = dist + ||z||^2
        }
        contrib = fdist;
        sm.u.red.ish[p] = fi;
        int gp = blk * MT + p;
        out[O_IDX + gp] = (float)fi;    // harness reads d_out as fp32
        wsi[W_IDX + gp] = fi;
        atomicAdd(&wsu[W_COUNTS + fi], 1u);
    }
    // loss partial: wave-0 reduction, one atomic per block
    if (t < 64) {
        for (int o = 32; o > 0; o >>= 1) contrib += __shfl_down(contrib, o, 64);
        if (t == 0) atomicAdd(&wsf[W_LOSS], contrib);
    }
    __syncthreads();
    // z_q gather
    float* outz = out + (size_t)blk * MT * DIM;
#pragma unroll
    for (int i = 0; i < (MT * DIM) / (256 * 4); i++) {
        int f4 = t + 256 * i;  // float4 index
        int p = f4 >> 5;
        int dq = f4 & 31;
        int ci = sm.u.red.ish[p];
        float4 v = *(const float4*)(emb + (size_t)ci * DIM + 4 * dq);
        *((float4*)outz + f4) = v;
    }
}

__global__ void k_finalize(const float* __restrict__ ema_cs, float* __restrict__ out,
                           float* __restrict__ wsf, unsigned* __restrict__ wsu) {
    __shared__ float s[KCL];
    __shared__ unsigned sc[KCL];
    int t = threadIdx.x;  // 512 threads
    unsigned c = wsu[W_COUNTS + t];
    float necs = ema_cs[t] * DECAY + (1.0f - DECAY) * (float)c;
    out[O_NECS + t] = necs;
    s[t] = necs;
    __syncthreads();
    for (int o = 256; o > 0; o >>= 1) {
        if (t < o) s[t] += s[t + o];
        __syncthreads();
    }
    float n = s[0];
    float cs = (necs + EPSV) / (n + (float)KCL * EPSV) * n;
    wsf[W_CS + t] = cs;
    // exclusive prefix sum of counts (Hillis-Steele)
    sc[t] = c;
    __syncthreads();
    for (int o = 1; o < KCL; o <<= 1) {
        unsigned v = (t >= o) ? sc[t - o] : 0u;
        __syncthreads();
        sc[t] += v;
        __syncthreads();
    }
    unsigned excl = sc[t] - c;
    wsu[W_OFF + t] = excl;
    wsu[W_CUR + t] = excl;
    if (t == 0) {
        out[O_LOSS] = CCOST * wsf[W_LOSS] / (float)((size_t)NPTS * DIM);
        wsu[W_OFF + KCL] = NPTS;   // sentinel for segment walking
    }
}

__global__ void k_scatter(unsigned* __restrict__ wsu, const int* __restrict__ wsi) {
    int p = blockIdx.x * blockDim.x + threadIdx.x;
    int k = wsi[W_IDX + p];
    unsigned pos = atomicAdd(&wsu[W_CUR + k], 1u);
    wsu[W_SORTED + pos] = (unsigned)p;
}

// dw accumulation, parallel over sorted points: 4096 blocks x 64 entries.
// Sorted => each 64-entry chunk spans ~1.1 clusters; flush partials by atomicAdd
// only at cluster boundaries.
__global__ __launch_bounds__(256) void k_dwseg(
    const float* __restrict__ z, float* __restrict__ wsf,
    const unsigned* __restrict__ wsu) {
    __shared__ unsigned soff[KCL + 1];
    __shared__ unsigned sidx[SEG];
    const int t = threadIdx.x;
    for (int i = t; i < KCL + 1; i += 256) soff[i] = wsu[W_OFF + i];
    const int base = blockIdx.x * SEG;
    if (t < SEG) sidx[t] = wsu[W_SORTED + base + t];
    __syncthreads();

    const int r = t >> 7;      // point row 0/1
    const int d = t & 127;     // dim lane
    const int pos0 = base + r;
    // binary search: largest k with soff[k] <= pos0
    int lo = 0, hi = KCL;
    while (lo < hi) {
        int mid = (lo + hi + 1) >> 1;
        if (soff[mid] <= (unsigned)pos0) lo = mid; else hi = mid - 1;
    }
    int curk = lo;
    float acc = 0.0f;
#pragma unroll 4
    for (int j = 0; j < SEG / 2; j++) {
        int pos = pos0 + 2 * j;
        unsigned p = sidx[pos - base];
        while ((unsigned)pos >= soff[curk + 1]) {
            if (acc != 0.0f) atomicAdd(&wsf[W_DW + curk * DIM + d], acc);
            acc = 0.0f;
            curk++;
        }
        acc += z[(size_t)p * DIM + d];
    }
    atomicAdd(&wsf[W_DW + curk * DIM + d], acc);
}

__global__ void k_emb(const float* __restrict__ ema_w, float* __restrict__ out,
                      const float* __restrict__ wsf) {
    int i = blockIdx.x * 256 + threadIdx.x;  // 0..65535
    int k = i >> 7;
    float dw = wsf[W_DW + i];
    float nw = ema_w[i] * DECAY + (1.0f - DECAY) * dw;
    out[O_NEMAW + i] = nw;
    out[O_NEMB + i] = nw / wsf[W_CS + k];
}

extern "C" void kernel_launch(void* const* d_in, const int* in_sizes, int n_in,
                              void* d_out, int out_size, void* d_ws, size_t ws_size,
                              hipStream_t stream) {
    const float* z = (const float*)d_in[0];
    const float* emb = (const float*)d_in[1];
    const float* ema_cs = (const float*)d_in[2];
    const float* ema_w = (const float*)d_in[3];
    float* out = (float*)d_out;
    float* wsf = (float*)d_ws;
    unsigned* wsu = (unsigned*)d_ws;
    int* wsi = (int*)d_ws;

    // zero counts[512] + loss + pad + dw[65536] in one contiguous memset
    hipMemsetAsync((char*)d_ws + (size_t)W_COUNTS * 4, 0,
                   (size_t)(W_DW + KCL * DIM - W_COUNTS) * 4, stream);

    k_enorm<<<2, 256, 0, stream>>>(emb, wsf);
    k_main<<<NPTS / MT, 256, 0, stream>>>(z, emb, out, wsf, wsu, wsi);
    k_finalize<<<1, KCL, 0, stream>>>(ema_cs, out, wsf, wsu);
    k_scatter<<<NPTS / 256, 256, 0, stream>>>(wsu, wsi);
    k_dwseg<<<NPTS / SEG, 256, 0, stream>>>(z, wsf, wsu);
    k_emb<<<KCL * DIM / 256, 256, 0, stream>>>(ema_w, out, wsf);
}

// Round 3
// 866.962 us; speedup vs baseline: 2.7781x; 1.4853x over previous
//
#include <hip/hip_runtime.h>

#define NPTS 262144
#define DIM 128
#define KCL 512

constexpr float DECAY = 0.99f;
constexpr float EPSV = 1e-5f;
constexpr float CCOST = 0.25f;

// ---- output layout (floats) ----
#define O_ZQ 0
#define O_LOSS (NPTS * DIM)
#define O_IDX (O_LOSS + 1)
#define O_NECS (O_IDX + NPTS)
#define O_NEMAW (O_NECS + KCL)
#define O_NEMB (O_NEMAW + KCL * DIM)

// ---- workspace layout (4-byte units) ----
#define W_ENORM 0                      // f32[512]
#define W_COUNTS 512                   // u32[512] (zeroed)
#define W_LOSS 1024                    // f32[1]   (zeroed)
#define W_NFLAG 1025                   // u32[1]   (zeroed)
#define W_DW 1088                      // f32[65536] (zeroed)
#define W_CS 66624                     // f32[512]
#define W_OFF 67136                    // u32[513]
#define W_CUR 67712                    // u32[512]
#define W_FLAG 68224                   // u32[2*32768] (gp, fdist bits)
#define W_IDX 133760                   // i32[N]
#define W_SORTED (W_IDX + NPTS)        // u32[N]

#define FLAGCAP 32768
#define MARGIN 0.005f
#define ESTR 136                       // e-tile LDS row stride in halves (128+8: bank-balanced, 16B-aligned rows)
#define SEG 64

using v8h = __attribute__((ext_vector_type(8))) _Float16;
using v4f = __attribute__((ext_vector_type(4))) float;

static __device__ inline _Float16 cvt_hi(float f) { return (_Float16)f; }

__global__ void k_enorm(const float* __restrict__ emb, float* __restrict__ wsf) {
    int k = blockIdx.x * blockDim.x + threadIdx.x;
    if (k < KCL) {
        const float4* row = (const float4*)(emb + (size_t)k * DIM);
        float s = 0.0f;
#pragma unroll
        for (int i = 0; i < DIM / 4; i++) {
            float4 v = row[i];
            s += v.x * v.x + v.y * v.y + v.z * v.z + v.w * v.w;
        }
        wsf[W_ENORM + k] = s;
    }
}

// Distance GEMM via fp16-split MFMA. Block: 256 thr, 64 points x all 512 clusters.
// Wave tile: 32 pts x 32 cl. A (z hi/lo) in registers, B (e hi/lo) staged in LDS.
__global__ __launch_bounds__(256, 3) void k_main(
    const float* __restrict__ z, const float* __restrict__ emb,
    float* __restrict__ out, float* __restrict__ wsf,
    unsigned* __restrict__ wsu, int* __restrict__ wsi) {
    __shared__ short ehs[64 * ESTR];
    __shared__ short els[64 * ESTR];
    __shared__ float sen[KCL];
    __shared__ float m1v[64];
    __shared__ int   m1i[64];
    __shared__ float m2v[64];
    __shared__ int   ishs[64];

    const int t = threadIdx.x;
    const int blk = blockIdx.x;
    const int w = t >> 6;
    const int lane = t & 63;
    const int col = lane & 15;
    const int quad = lane >> 4;
    const int wrow = w & 1;    // which 32-point half
    const int wcol = w >> 1;   // which 32-cluster half of each tile

    // stage enorm to LDS (sync provided by first kt-loop barrier)
    sen[t] = wsf[W_ENORM + t];
    sen[t + 256] = wsf[W_ENORM + t + 256];

    // ---- A fragments: z hi/lo in registers, + ||z||^2 partials ----
    v8h ah[2][4], al[2][4];
    float zn[2];
#pragma unroll
    for (int mt = 0; mt < 2; mt++) {
        zn[mt] = 0.0f;
        const float* zr = z + (size_t)(blk * 64 + wrow * 32 + mt * 16 + col) * DIM;
#pragma unroll
        for (int ks = 0; ks < 4; ks++) {
            const float* p = zr + ks * 32 + quad * 8;
            float4 a = *(const float4*)p;
            float4 b = *(const float4*)(p + 4);
            float f[8] = {a.x, a.y, a.z, a.w, b.x, b.y, b.z, b.w};
#pragma unroll
            for (int j = 0; j < 8; j++) {
                _Float16 h = cvt_hi(f[j]);
                float r = f[j] - (float)h;
                ah[mt][ks][j] = h;
                al[mt][ks][j] = (_Float16)r;
                zn[mt] += f[j] * f[j];
            }
        }
        zn[mt] += __shfl_xor(zn[mt], 16);
        zn[mt] += __shfl_xor(zn[mt], 32);
    }

    float rv1[8], rv2[8];
    int ri1[8];
#pragma unroll
    for (int s = 0; s < 8; s++) { rv1[s] = 3.4e38f; rv2[s] = 3.4e38f; ri1[s] = 0; }

    for (int kt = 0; kt < 8; kt++) {
        __syncthreads();
        // ---- stage e tile (64 clusters x 128 d) as fp16 hi/lo ----
#pragma unroll
        for (int i = 0; i < 8; i++) {
            int f4 = t + 256 * i;
            int n = f4 >> 5, dq = f4 & 31;
            float4 v = *(const float4*)(emb + (size_t)(kt * 64 + n) * DIM + 4 * dq);
            float f[4] = {v.x, v.y, v.z, v.w};
            short hb[4], lb[4];
#pragma unroll
            for (int j = 0; j < 4; j++) {
                _Float16 h = cvt_hi(f[j]);
                float r = f[j] - (float)h;
                _Float16 l = (_Float16)r;
                hb[j] = __builtin_bit_cast(short, h);
                lb[j] = __builtin_bit_cast(short, l);
            }
            *(short4*)&ehs[n * ESTR + 4 * dq] = make_short4(hb[0], hb[1], hb[2], hb[3]);
            *(short4*)&els[n * ESTR + 4 * dq] = make_short4(lb[0], lb[1], lb[2], lb[3]);
        }
        __syncthreads();

        v4f acc[2][2];
#pragma unroll
        for (int mt = 0; mt < 2; mt++)
#pragma unroll
            for (int nt = 0; nt < 2; nt++) { v4f zz = {0.f, 0.f, 0.f, 0.f}; acc[mt][nt] = zz; }

#pragma unroll
        for (int ks = 0; ks < 4; ks++) {
            v8h bh[2], bl[2];
#pragma unroll
            for (int nt = 0; nt < 2; nt++) {
                int off = (wcol * 32 + nt * 16 + col) * ESTR + ks * 32 + quad * 8;
                bh[nt] = *(const v8h*)&ehs[off];
                bl[nt] = *(const v8h*)&els[off];
            }
            // grouped by term: dependency distance 4 on each acc
#pragma unroll
            for (int nt = 0; nt < 2; nt++)
#pragma unroll
                for (int mt = 0; mt < 2; mt++)
                    acc[mt][nt] = __builtin_amdgcn_mfma_f32_16x16x32_f16(ah[mt][ks], bh[nt], acc[mt][nt], 0, 0, 0);
#pragma unroll
            for (int nt = 0; nt < 2; nt++)
#pragma unroll
                for (int mt = 0; mt < 2; mt++)
                    acc[mt][nt] = __builtin_amdgcn_mfma_f32_16x16x32_f16(al[mt][ks], bh[nt], acc[mt][nt], 0, 0, 0);
#pragma unroll
            for (int nt = 0; nt < 2; nt++)
#pragma unroll
                for (int mt = 0; mt < 2; mt++)
                    acc[mt][nt] = __builtin_amdgcn_mfma_f32_16x16x32_f16(ah[mt][ks], bl[nt], acc[mt][nt], 0, 0, 0);
        }

        // ---- tile epilogue: per-lane running top-2 per point slot ----
#pragma unroll
        for (int nt = 0; nt < 2; nt++) {
            int kbase = kt * 64 + wcol * 32 + nt * 16 + col;
            float en = sen[kbase];
#pragma unroll
            for (int mt = 0; mt < 2; mt++)
#pragma unroll
                for (int r = 0; r < 4; r++) {
                    int s = mt * 4 + r;
                    float dist = en - 2.0f * acc[mt][nt][r];
                    if (dist < rv1[s]) { rv2[s] = rv1[s]; rv1[s] = dist; ri1[s] = kbase; }
                    else if (dist < rv2[s]) rv2[s] = dist;
                }
        }
    }

    // ---- butterfly merge across the 16 cols ----
#pragma unroll
    for (int m = 1; m < 16; m <<= 1) {
#pragma unroll
        for (int s = 0; s < 8; s++) {
            float c1 = __shfl_xor(rv1[s], m);
            int ci1 = __shfl_xor(ri1[s], m);
            float c2 = __shfl_xor(rv2[s], m);
            if (c1 < rv1[s] || (c1 == rv1[s] && ci1 < ri1[s])) {
                rv2[s] = fminf(rv1[s], c2);
                rv1[s] = c1; ri1[s] = ci1;
            } else {
                rv2[s] = fminf(rv2[s], c1);
            }
        }
    }

    // zn for the points this lane's quad owns (uniform exec)
    float znp[8];
#pragma unroll
    for (int s = 0; s < 8; s++) znp[s] = __shfl(zn[s >> 2], quad * 4 + (s & 3));

    __syncthreads();  // e-tile no longer needed; m1* reuse is fresh arrays
    if (wcol == 0 && col == 0) {
#pragma unroll
        for (int s = 0; s < 8; s++) {
            int p = wrow * 32 + (s >> 2) * 16 + quad * 4 + (s & 3);
            m1v[p] = rv1[s]; m1i[p] = ri1[s]; m2v[p] = rv2[s];
        }
    }
    __syncthreads();
    float lossacc = 0.0f;
    if (wcol == 1 && col == 0) {
#pragma unroll
        for (int s = 0; s < 8; s++) {
            int p = wrow * 32 + (s >> 2) * 16 + quad * 4 + (s & 3);
            float a1 = m1v[p]; int ai1 = m1i[p]; float a2 = m2v[p];
            float v1, v2; int i1;
            if (a1 < rv1[s] || (a1 == rv1[s] && ai1 < ri1[s])) {
                v1 = a1; i1 = ai1; v2 = fminf(a2, rv1[s]);
            } else {
                v1 = rv1[s]; i1 = ri1[s]; v2 = fminf(rv2[s], a1);
            }
            float fd = v1 + znp[s];
            int gp = blk * 64 + p;
            out[O_IDX + gp] = (float)i1;
            wsi[W_IDX + gp] = i1;
            ishs[p] = i1;
            atomicAdd(&wsu[W_COUNTS + i1], 1u);
            lossacc += fd;
            if (v2 - v1 < MARGIN) {
                unsigned pos = atomicAdd(&wsu[W_NFLAG], 1u);
                if (pos < FLAGCAP) {
                    wsu[W_FLAG + 2 * pos] = (unsigned)gp;
                    wsu[W_FLAG + 2 * pos + 1] = __float_as_uint(fd);
                }
            }
        }
    }
    for (int o = 32; o > 0; o >>= 1) lossacc += __shfl_down(lossacc, o);
    if (lane == 0) atomicAdd(&wsf[W_LOSS], lossacc);

    __syncthreads();
    // ---- z_q gather ----
    float* outz = out + (size_t)blk * 64 * DIM;
#pragma unroll
    for (int i = 0; i < 8; i++) {
        int f4 = t + 256 * i;
        int p = f4 >> 5, dq = f4 & 31;
        int ci = ishs[p];
        float4 v = *(const float4*)(emb + (size_t)ci * DIM + 4 * dq);
        *((float4*)outz + f4) = v;
    }
}

// fp64 full-scan recheck for near-tie points (fixes idx, counts, loss, z_q)
__global__ __launch_bounds__(256) void k_recheck(
    const float* __restrict__ z, const float* __restrict__ emb,
    float* __restrict__ out, float* __restrict__ wsf,
    unsigned* __restrict__ wsu, int* __restrict__ wsi) {
    __shared__ float zrow[DIM];
    __shared__ double sd[256];
    __shared__ int si[256];
    __shared__ int schg, snew;
    const int t = threadIdx.x;
    unsigned nf = wsu[W_NFLAG];
    if (nf > FLAGCAP) nf = FLAGCAP;
    for (unsigned fi = blockIdx.x; fi < nf; fi += gridDim.x) {
        unsigned gp = wsu[W_FLAG + 2 * fi];
        float fd_prov = __uint_as_float(wsu[W_FLAG + 2 * fi + 1]);
        __syncthreads();
        if (t < DIM) zrow[t] = z[(size_t)gp * DIM + t];
        __syncthreads();
        double best = 1e300; int bi = 0;
        for (int c = t; c < KCL; c += 256) {
            const float* er = emb + (size_t)c * DIM;
            double d = 0.0;
            for (int dd = 0; dd < DIM; dd++) {
                double df = (double)zrow[dd] - (double)er[dd];
                d += df * df;
            }
            if (d < best) { best = d; bi = c; }
        }
        sd[t] = best; si[t] = bi;
        __syncthreads();
        for (int o = 128; o > 0; o >>= 1) {
            if (t < o) {
                if (sd[t + o] < sd[t] || (sd[t + o] == sd[t] && si[t + o] < si[t])) {
                    sd[t] = sd[t + o]; si[t] = si[t + o];
                }
            }
            __syncthreads();
        }
        if (t == 0) {
            int inew = si[0];
            int iold = wsi[W_IDX + gp];
            snew = inew;
            schg = (inew != iold);
            atomicAdd(&wsf[W_LOSS], (float)sd[0] - fd_prov);
            if (inew != iold) {
                wsi[W_IDX + gp] = inew;
                out[O_IDX + gp] = (float)inew;
                atomicAdd(&wsu[W_COUNTS + iold], (unsigned)-1);
                atomicAdd(&wsu[W_COUNTS + inew], 1u);
            }
        }
        __syncthreads();
        if (schg && t < DIM) out[(size_t)gp * DIM + t] = emb[(size_t)snew * DIM + t];
        __syncthreads();
    }
}

__global__ void k_finalize(const float* __restrict__ ema_cs, float* __restrict__ out,
                           float* __restrict__ wsf, unsigned* __restrict__ wsu) {
    __shared__ float s[KCL];
    __shared__ unsigned sc[KCL];
    int t = threadIdx.x;  // 512 threads
    unsigned c = wsu[W_COUNTS + t];
    float necs = ema_cs[t] * DECAY + (1.0f - DECAY) * (float)c;
    out[O_NECS + t] = necs;
    s[t] = necs;
    __syncthreads();
    for (int o = 256; o > 0; o >>= 1) {
        if (t < o) s[t] += s[t + o];
        __syncthreads();
    }
    float n = s[0];
    float cs = (necs + EPSV) / (n + (float)KCL * EPSV) * n;
    wsf[W_CS + t] = cs;
    sc[t] = c;
    __syncthreads();
    for (int o = 1; o < KCL; o <<= 1) {
        unsigned v = (t >= o) ? sc[t - o] : 0u;
        __syncthreads();
        sc[t] += v;
        __syncthreads();
    }
    unsigned excl = sc[t] - c;
    wsu[W_OFF + t] = excl;
    wsu[W_CUR + t] = excl;
    if (t == 0) {
        out[O_LOSS] = CCOST * wsf[W_LOSS] / (float)((size_t)NPTS * DIM);
        wsu[W_OFF + KCL] = NPTS;
    }
}

__global__ void k_scatter(unsigned* __restrict__ wsu, const int* __restrict__ wsi) {
    int p = blockIdx.x * blockDim.x + threadIdx.x;
    int k = wsi[W_IDX + p];
    unsigned pos = atomicAdd(&wsu[W_CUR + k], 1u);
    wsu[W_SORTED + pos] = (unsigned)p;
}

__global__ __launch_bounds__(256) void k_dwseg(
    const float* __restrict__ z, float* __restrict__ wsf,
    const unsigned* __restrict__ wsu) {
    __shared__ unsigned soff[KCL + 1];
    __shared__ unsigned sidx[SEG];
    const int t = threadIdx.x;
    for (int i = t; i < KCL + 1; i += 256) soff[i] = wsu[W_OFF + i];
    const int base = blockIdx.x * SEG;
    if (t < SEG) sidx[t] = wsu[W_SORTED + base + t];
    __syncthreads();

    const int r = t >> 7;
    const int d = t & 127;
    const int pos0 = base + r;
    int lo = 0, hi = KCL;
    while (lo < hi) {
        int mid = (lo + hi + 1) >> 1;
        if (soff[mid] <= (unsigned)pos0) lo = mid; else hi = mid - 1;
    }
    int curk = lo;
    float acc = 0.0f;
#pragma unroll 4
    for (int j = 0; j < SEG / 2; j++) {
        int pos = pos0 + 2 * j;
        unsigned p = sidx[pos - base];
        while ((unsigned)pos >= soff[curk + 1]) {
            if (acc != 0.0f) atomicAdd(&wsf[W_DW + curk * DIM + d], acc);
            acc = 0.0f;
            curk++;
        }
        acc += z[(size_t)p * DIM + d];
    }
    atomicAdd(&wsf[W_DW + curk * DIM + d], acc);
}

__global__ void k_emb(const float* __restrict__ ema_w, float* __restrict__ out,
                      const float* __restrict__ wsf) {
    int i = blockIdx.x * 256 + threadIdx.x;
    int k = i >> 7;
    float dw = wsf[W_DW + i];
    float nw = ema_w[i] * DECAY + (1.0f - DECAY) * dw;
    out[O_NEMAW + i] = nw;
    out[O_NEMB + i] = nw / wsf[W_CS + k];
}

extern "C" void kernel_launch(void* const* d_in, const int* in_sizes, int n_in,
                              void* d_out, int out_size, void* d_ws, size_t ws_size,
                              hipStream_t stream) {
    const float* z = (const float*)d_in[0];
    const float* emb = (const float*)d_in[1];
    const float* ema_cs = (const float*)d_in[2];
    const float* ema_w = (const float*)d_in[3];
    float* out = (float*)d_out;
    float* wsf = (float*)d_ws;
    unsigned* wsu = (unsigned*)d_ws;
    int* wsi = (int*)d_ws;

    // zero counts + loss + nflag + dw (contiguous region)
    hipMemsetAsync((char*)d_ws + (size_t)W_COUNTS * 4, 0,
                   (size_t)(W_DW + KCL * DIM - W_COUNTS) * 4, stream);

    k_enorm<<<2, 256, 0, stream>>>(emb, wsf);
    k_main<<<NPTS / 64, 256, 0, stream>>>(z, emb, out, wsf, wsu, wsi);
    k_recheck<<<1024, 256, 0, stream>>>(z, emb, out, wsf, wsu, wsi);
    k_finalize<<<1, KCL, 0, stream>>>(ema_cs, out, wsf, wsu);
    k_scatter<<<NPTS / 256, 256, 0, stream>>>(wsu, wsi);
    k_dwseg<<<NPTS / SEG, 256, 0, stream>>>(z, wsf, wsu);
    k_emb<<<KCL * DIM / 256, 256, 0, stream>>>(ema_w, out, wsf);
}

// Round 4
// 824.437 us; speedup vs baseline: 2.9214x; 1.0516x over previous
//
#include <hip/hip_runtime.h>

#define NPTS 262144
#define DIM 128
#define KCL 512

constexpr float DECAY = 0.99f;
constexpr float EPSV = 1e-5f;
constexpr float CCOST = 0.25f;

// ---- output layout (floats) ----
#define O_ZQ 0
#define O_LOSS (NPTS * DIM)
#define O_IDX (O_LOSS + 1)
#define O_NECS (O_IDX + NPTS)
#define O_NEMAW (O_NECS + KCL)
#define O_NEMB (O_NEMAW + KCL * DIM)

// ---- workspace layout (4-byte units) ----
#define W_ENORM 0                      // f32[512]
#define W_COUNTS 512                   // u32[512] (zeroed)
#define W_LOSS 1024                    // f32[1]   (zeroed)
#define W_NFLAG 1025                   // u32[1]   (zeroed)
#define W_DW 1088                      // f32[65536] (zeroed)
#define W_CS 66624                     // f32[512]
#define W_OFF 67136                    // u32[513]
#define W_CUR 67712                    // u32[512]
#define W_EHI 68224                    // u16[65536] packed fp16-hi, MFMA-frag order
#define W_ELO 100992                   // u16[65536] packed fp16-lo
#define W_FLAG 133760                  // u32[2*FLAGCAP]
#define FLAGCAP 32768
#define W_IDX 199296                   // i32[N]
#define W_SORTED (W_IDX + NPTS)        // u32[N]

#define MARGIN 0.005f
#define SEG 64

using v8h = __attribute__((ext_vector_type(8))) _Float16;
using v4f = __attribute__((ext_vector_type(4))) float;

__global__ void k_enorm(const float* __restrict__ emb, float* __restrict__ wsf) {
    int k = blockIdx.x * blockDim.x + threadIdx.x;
    if (k < KCL) {
        const float4* row = (const float4*)(emb + (size_t)k * DIM);
        float s = 0.0f;
#pragma unroll
        for (int i = 0; i < DIM / 4; i++) {
            float4 v = row[i];
            s += v.x * v.x + v.y * v.y + v.z * v.z + v.w * v.w;
        }
        wsf[W_ENORM + k] = s;
    }
}

// One-time embedding fp16-split into MFMA B-fragment order:
// packed[((g*4+ks)*64 + lane)*8 + j] = e[g*16 + (lane&15)][ks*32 + (lane>>4)*8 + j]
__global__ void k_prep(const float* __restrict__ emb,
                       unsigned short* __restrict__ ehi,
                       unsigned short* __restrict__ elo) {
    int gi = blockIdx.x * 256 + threadIdx.x;  // 0..8191
    int lane = gi & 63, ks = (gi >> 6) & 3, g = gi >> 8;
    int col = lane & 15, quad = lane >> 4;
    const float* src = emb + (size_t)(g * 16 + col) * DIM + ks * 32 + quad * 8;
    float4 a = *(const float4*)src;
    float4 b = *(const float4*)(src + 4);
    float f[8] = {a.x, a.y, a.z, a.w, b.x, b.y, b.z, b.w};
    union { unsigned short s[8]; int4 v; } uh, ul;
#pragma unroll
    for (int j = 0; j < 8; j++) {
        _Float16 h = (_Float16)f[j];
        float r = f[j] - (float)h;
        _Float16 l = (_Float16)r;
        uh.s[j] = __builtin_bit_cast(unsigned short, h);
        ul.s[j] = __builtin_bit_cast(unsigned short, l);
    }
    *(int4*)&ehi[(size_t)gi * 8] = uh.v;
    *(int4*)&elo[(size_t)gi * 8] = ul.v;
}

// Distance GEMM via fp16-split MFMA. 64 points x 512 clusters per block.
// B tiles staged to LDS as a pure memcpy of pre-split fragments (no conversion,
// lane-linear => conflict-free).
__global__ __launch_bounds__(256, 3) void k_main(
    const float* __restrict__ z, const float* __restrict__ emb,
    const unsigned short* __restrict__ ehi, const unsigned short* __restrict__ elo,
    float* __restrict__ out, float* __restrict__ wsf,
    unsigned* __restrict__ wsu, int* __restrict__ wsi) {
    __shared__ short seh[8192];   // 16 KB: 64 clusters x 128 halves (frag order)
    __shared__ short sel[8192];
    __shared__ float sen[KCL];
    __shared__ float m1v[64];
    __shared__ int   m1i[64];
    __shared__ float m2v[64];
    __shared__ int   ishs[64];

    const int t = threadIdx.x;
    const int blk = blockIdx.x;
    const int w = t >> 6;
    const int lane = t & 63;
    const int col = lane & 15;
    const int quad = lane >> 4;
    const int wrow = w & 1;    // 32-point half
    const int wcol = w >> 1;   // 32-cluster half of each 64-tile

    sen[t] = wsf[W_ENORM + t];
    sen[t + 256] = wsf[W_ENORM + t + 256];

    // ---- A fragments: z hi/lo in registers, + ||z||^2 ----
    v8h ah[2][4], al[2][4];
    float zn[2];
#pragma unroll
    for (int mt = 0; mt < 2; mt++) {
        zn[mt] = 0.0f;
        const float* zr = z + (size_t)(blk * 64 + wrow * 32 + mt * 16 + col) * DIM;
#pragma unroll
        for (int ks = 0; ks < 4; ks++) {
            const float* p = zr + ks * 32 + quad * 8;
            float4 a = *(const float4*)p;
            float4 b = *(const float4*)(p + 4);
            float f[8] = {a.x, a.y, a.z, a.w, b.x, b.y, b.z, b.w};
#pragma unroll
            for (int j = 0; j < 8; j++) {
                _Float16 h = (_Float16)f[j];
                float r = f[j] - (float)h;
                ah[mt][ks][j] = h;
                al[mt][ks][j] = (_Float16)r;
                zn[mt] += f[j] * f[j];
            }
        }
        zn[mt] += __shfl_xor(zn[mt], 16);
        zn[mt] += __shfl_xor(zn[mt], 32);
    }

    float rv1[8], rv2[8];
    int ri1[8];
#pragma unroll
    for (int s = 0; s < 8; s++) { rv1[s] = 3.4e38f; rv2[s] = 3.4e38f; ri1[s] = 0; }

    for (int kt = 0; kt < 8; kt++) {
        __syncthreads();
        // ---- stage 32 KB of pre-split fragments (pure memcpy) ----
        {
            const int4* srch = (const int4*)(ehi + (size_t)kt * 8192);
            const int4* srcl = (const int4*)(elo + (size_t)kt * 8192);
#pragma unroll
            for (int i = 0; i < 4; i++) {
                int idx = t + 256 * i;
                ((int4*)seh)[idx] = srch[idx];
                ((int4*)sel)[idx] = srcl[idx];
            }
        }
        __syncthreads();

        v4f acc[2][2];
#pragma unroll
        for (int mt = 0; mt < 2; mt++)
#pragma unroll
            for (int nt = 0; nt < 2; nt++) { v4f zz = {0.f, 0.f, 0.f, 0.f}; acc[mt][nt] = zz; }

#pragma unroll
        for (int ks = 0; ks < 4; ks++) {
            v8h bh[2], bl[2];
#pragma unroll
            for (int nt = 0; nt < 2; nt++) {
                int off = ((wcol * 2 + nt) * 4 + ks) * 512 + lane * 8;
                bh[nt] = *(const v8h*)&seh[off];
                bl[nt] = *(const v8h*)&sel[off];
            }
#pragma unroll
            for (int nt = 0; nt < 2; nt++)
#pragma unroll
                for (int mt = 0; mt < 2; mt++)
                    acc[mt][nt] = __builtin_amdgcn_mfma_f32_16x16x32_f16(ah[mt][ks], bh[nt], acc[mt][nt], 0, 0, 0);
#pragma unroll
            for (int nt = 0; nt < 2; nt++)
#pragma unroll
                for (int mt = 0; mt < 2; mt++)
                    acc[mt][nt] = __builtin_amdgcn_mfma_f32_16x16x32_f16(al[mt][ks], bh[nt], acc[mt][nt], 0, 0, 0);
#pragma unroll
            for (int nt = 0; nt < 2; nt++)
#pragma unroll
                for (int mt = 0; mt < 2; mt++)
                    acc[mt][nt] = __builtin_amdgcn_mfma_f32_16x16x32_f16(ah[mt][ks], bl[nt], acc[mt][nt], 0, 0, 0);
        }

        // ---- per-lane running top-2 (tie -> lowest index via strict < and ascending k) ----
#pragma unroll
        for (int nt = 0; nt < 2; nt++) {
            int kbase = kt * 64 + wcol * 32 + nt * 16 + col;
            float en = sen[kbase];
#pragma unroll
            for (int mt = 0; mt < 2; mt++)
#pragma unroll
                for (int r = 0; r < 4; r++) {
                    int s = mt * 4 + r;
                    float dist = en - 2.0f * acc[mt][nt][r];
                    if (dist < rv1[s]) { rv2[s] = rv1[s]; rv1[s] = dist; ri1[s] = kbase; }
                    else if (dist < rv2[s]) rv2[s] = dist;
                }
        }
    }

    // ---- butterfly merge across the 16 cols ----
#pragma unroll
    for (int m = 1; m < 16; m <<= 1) {
#pragma unroll
        for (int s = 0; s < 8; s++) {
            float c1 = __shfl_xor(rv1[s], m);
            int ci1 = __shfl_xor(ri1[s], m);
            float c2 = __shfl_xor(rv2[s], m);
            if (c1 < rv1[s] || (c1 == rv1[s] && ci1 < ri1[s])) {
                rv2[s] = fminf(rv1[s], c2);
                rv1[s] = c1; ri1[s] = ci1;
            } else {
                rv2[s] = fminf(rv2[s], c1);
            }
        }
    }

    float znp[8];
#pragma unroll
    for (int s = 0; s < 8; s++) znp[s] = __shfl(zn[s >> 2], quad * 4 + (s & 3));

    if (wcol == 0 && col == 0) {
#pragma unroll
        for (int s = 0; s < 8; s++) {
            int p = wrow * 32 + (s >> 2) * 16 + quad * 4 + (s & 3);
            m1v[p] = rv1[s]; m1i[p] = ri1[s]; m2v[p] = rv2[s];
        }
    }
    __syncthreads();
    float lossacc = 0.0f;
    if (wcol == 1 && col == 0) {
#pragma unroll
        for (int s = 0; s < 8; s++) {
            int p = wrow * 32 + (s >> 2) * 16 + quad * 4 + (s & 3);
            float a1 = m1v[p]; int ai1 = m1i[p]; float a2 = m2v[p];
            float v1, v2; int i1;
            if (a1 < rv1[s] || (a1 == rv1[s] && ai1 < ri1[s])) {
                v1 = a1; i1 = ai1; v2 = fminf(a2, rv1[s]);
            } else {
                v1 = rv1[s]; i1 = ri1[s]; v2 = fminf(rv2[s], a1);
            }
            float fd = v1 + znp[s];
            int gp = blk * 64 + p;
            out[O_IDX + gp] = (float)i1;
            wsi[W_IDX + gp] = i1;
            ishs[p] = i1;
            atomicAdd(&wsu[W_COUNTS + i1], 1u);
            lossacc += fd;
            if (v2 - v1 < MARGIN) {
                unsigned pos = atomicAdd(&wsu[W_NFLAG], 1u);
                if (pos < FLAGCAP) {
                    wsu[W_FLAG + 2 * pos] = (unsigned)gp;
                    wsu[W_FLAG + 2 * pos + 1] = __float_as_uint(fd);
                }
            }
        }
    }
    for (int o = 32; o > 0; o >>= 1) lossacc += __shfl_down(lossacc, o);
    if (lane == 0) atomicAdd(&wsf[W_LOSS], lossacc);

    __syncthreads();
    // ---- z_q gather ----
    float* outz = out + (size_t)blk * 64 * DIM;
#pragma unroll
    for (int i = 0; i < 8; i++) {
        int f4 = t + 256 * i;
        int p = f4 >> 5, dq = f4 & 31;
        int ci = ishs[p];
        float4 v = *(const float4*)(emb + (size_t)ci * DIM + 4 * dq);
        *((float4*)outz + f4) = v;
    }
}

// fp64 full-scan recheck for near-tie points
__global__ __launch_bounds__(256) void k_recheck(
    const float* __restrict__ z, const float* __restrict__ emb,
    float* __restrict__ out, float* __restrict__ wsf,
    unsigned* __restrict__ wsu, int* __restrict__ wsi) {
    __shared__ float zrow[DIM];
    __shared__ double sd[256];
    __shared__ int si[256];
    __shared__ int schg, snew;
    const int t = threadIdx.x;
    unsigned nf = wsu[W_NFLAG];
    if (nf > FLAGCAP) nf = FLAGCAP;
    for (unsigned fi = blockIdx.x; fi < nf; fi += gridDim.x) {
        unsigned gp = wsu[W_FLAG + 2 * fi];
        float fd_prov = __uint_as_float(wsu[W_FLAG + 2 * fi + 1]);
        __syncthreads();
        if (t < DIM) zrow[t] = z[(size_t)gp * DIM + t];
        __syncthreads();
        double best = 1e300; int bi = 0;
        for (int c = t; c < KCL; c += 256) {
            const float* er = emb + (size_t)c * DIM;
            double d = 0.0;
            for (int dd = 0; dd < DIM; dd++) {
                double df = (double)zrow[dd] - (double)er[dd];
                d += df * df;
            }
            if (d < best) { best = d; bi = c; }
        }
        sd[t] = best; si[t] = bi;
        __syncthreads();
        for (int o = 128; o > 0; o >>= 1) {
            if (t < o) {
                if (sd[t + o] < sd[t] || (sd[t + o] == sd[t] && si[t + o] < si[t])) {
                    sd[t] = sd[t + o]; si[t] = si[t + o];
                }
            }
            __syncthreads();
        }
        if (t == 0) {
            int inew = si[0];
            int iold = wsi[W_IDX + gp];
            snew = inew;
            schg = (inew != iold);
            atomicAdd(&wsf[W_LOSS], (float)sd[0] - fd_prov);
            if (inew != iold) {
                wsi[W_IDX + gp] = inew;
                out[O_IDX + gp] = (float)inew;
                atomicAdd(&wsu[W_COUNTS + iold], (unsigned)-1);
                atomicAdd(&wsu[W_COUNTS + inew], 1u);
            }
        }
        __syncthreads();
        if (schg && t < DIM) out[(size_t)gp * DIM + t] = emb[(size_t)snew * DIM + t];
        __syncthreads();
    }
}

__global__ void k_finalize(const float* __restrict__ ema_cs, float* __restrict__ out,
                           float* __restrict__ wsf, unsigned* __restrict__ wsu) {
    __shared__ float s[KCL];
    __shared__ unsigned sc[KCL];
    int t = threadIdx.x;  // 512 threads
    unsigned c = wsu[W_COUNTS + t];
    float necs = ema_cs[t] * DECAY + (1.0f - DECAY) * (float)c;
    out[O_NECS + t] = necs;
    s[t] = necs;
    __syncthreads();
    for (int o = 256; o > 0; o >>= 1) {
        if (t < o) s[t] += s[t + o];
        __syncthreads();
    }
    float n = s[0];
    float cs = (necs + EPSV) / (n + (float)KCL * EPSV) * n;
    wsf[W_CS + t] = cs;
    sc[t] = c;
    __syncthreads();
    for (int o = 1; o < KCL; o <<= 1) {
        unsigned v = (t >= o) ? sc[t - o] : 0u;
        __syncthreads();
        sc[t] += v;
        __syncthreads();
    }
    unsigned excl = sc[t] - c;
    wsu[W_OFF + t] = excl;
    wsu[W_CUR + t] = excl;
    if (t == 0) {
        out[O_LOSS] = CCOST * wsf[W_LOSS] / (float)((size_t)NPTS * DIM);
        wsu[W_OFF + KCL] = NPTS;
    }
}

__global__ void k_scatter(unsigned* __restrict__ wsu, const int* __restrict__ wsi) {
    int p = blockIdx.x * blockDim.x + threadIdx.x;
    int k = wsi[W_IDX + p];
    unsigned pos = atomicAdd(&wsu[W_CUR + k], 1u);
    wsu[W_SORTED + pos] = (unsigned)p;
}

__global__ __launch_bounds__(256) void k_dwseg(
    const float* __restrict__ z, float* __restrict__ wsf,
    const unsigned* __restrict__ wsu) {
    __shared__ unsigned soff[KCL + 1];
    __shared__ unsigned sidx[SEG];
    const int t = threadIdx.x;
    for (int i = t; i < KCL + 1; i += 256) soff[i] = wsu[W_OFF + i];
    const int base = blockIdx.x * SEG;
    if (t < SEG) sidx[t] = wsu[W_SORTED + base + t];
    __syncthreads();

    const int r = t >> 7;
    const int d = t & 127;
    const int pos0 = base + r;
    int lo = 0, hi = KCL;
    while (lo < hi) {
        int mid = (lo + hi + 1) >> 1;
        if (soff[mid] <= (unsigned)pos0) lo = mid; else hi = mid - 1;
    }
    int curk = lo;
    float acc = 0.0f;
#pragma unroll 4
    for (int j = 0; j < SEG / 2; j++) {
        int pos = pos0 + 2 * j;
        unsigned p = sidx[pos - base];
        while ((unsigned)pos >= soff[curk + 1]) {
            if (acc != 0.0f) atomicAdd(&wsf[W_DW + curk * DIM + d], acc);
            acc = 0.0f;
            curk++;
        }
        acc += z[(size_t)p * DIM + d];
    }
    atomicAdd(&wsf[W_DW + curk * DIM + d], acc);
}

__global__ void k_emb(const float* __restrict__ ema_w, float* __restrict__ out,
                      const float* __restrict__ wsf) {
    int i = blockIdx.x * 256 + threadIdx.x;
    int k = i >> 7;
    float dw = wsf[W_DW + i];
    float nw = ema_w[i] * DECAY + (1.0f - DECAY) * dw;
    out[O_NEMAW + i] = nw;
    out[O_NEMB + i] = nw / wsf[W_CS + k];
}

extern "C" void kernel_launch(void* const* d_in, const int* in_sizes, int n_in,
                              void* d_out, int out_size, void* d_ws, size_t ws_size,
                              hipStream_t stream) {
    const float* z = (const float*)d_in[0];
    const float* emb = (const float*)d_in[1];
    const float* ema_cs = (const float*)d_in[2];
    const float* ema_w = (const float*)d_in[3];
    float* out = (float*)d_out;
    float* wsf = (float*)d_ws;
    unsigned* wsu = (unsigned*)d_ws;
    int* wsi = (int*)d_ws;
    unsigned short* ehi = (unsigned short*)(wsu + W_EHI);
    unsigned short* elo = (unsigned short*)(wsu + W_ELO);

    // zero counts + loss + nflag + dw (contiguous region)
    hipMemsetAsync((char*)d_ws + (size_t)W_COUNTS * 4, 0,
                   (size_t)(W_DW + KCL * DIM - W_COUNTS) * 4, stream);

    k_enorm<<<2, 256, 0, stream>>>(emb, wsf);
    k_prep<<<32, 256, 0, stream>>>(emb, ehi, elo);
    k_main<<<NPTS / 64, 256, 0, stream>>>(z, emb, ehi, elo, out, wsf, wsu, wsi);
    k_recheck<<<1024, 256, 0, stream>>>(z, emb, out, wsf, wsu, wsi);
    k_finalize<<<1, KCL, 0, stream>>>(ema_cs, out, wsf, wsu);
    k_scatter<<<NPTS / 256, 256, 0, stream>>>(wsu, wsi);
    k_dwseg<<<NPTS / SEG, 256, 0, stream>>>(z, wsf, wsu);
    k_emb<<<KCL * DIM / 256, 256, 0, stream>>>(ema_w, out, wsf);
}